// Round 9
// baseline (181.220 us; speedup 1.0000x reference)
//
#include <hip/hip_runtime.h>
#include <math.h>

#define B_  8
#define C_  64
#define H_  128
#define W_  128
#define KK_ 9
#define CO_ 64
#define HW_ (H_*W_)
#define CK_ 576

typedef _Float16 f16x8 __attribute__((ext_vector_type(8)));
typedef _Float16 h2    __attribute__((ext_vector_type(2)));
typedef __attribute__((ext_vector_type(4))) float f32x4;

__device__ inline unsigned pkrtz(float a, float b){
    auto v = __builtin_amdgcn_cvt_pkrtz(a, b);   // __fp16x2 on this toolchain
    union{decltype(v) h; unsigned u;} c; c.h = v; return c.u;
}
__device__ inline h2 u2h(unsigned u){ union{unsigned x; h2 h;} c; c.x = u; return c.h; }
__device__ inline unsigned h2u(h2 v){ union{h2 h; unsigned u;} c; c.h = v; return c.u; }
__device__ inline unsigned short f2h(float f){
    _Float16 h = (_Float16)f;
    union{_Float16 h; unsigned short s;} c; c.h = h; return c.s;
}
// broadcast lo/hi f16 of a dword into both halves (1 v_perm_b32 each)
__device__ inline h2 bcast_lo(unsigned u){ return u2h(__builtin_amdgcn_perm(u, u, 0x01000100)); }
__device__ inline h2 bcast_hi(unsigned u){ return u2h(__builtin_amdgcn_perm(u, u, 0x03020302)); }

// ---- transpose_prep: fused x NCHW->NHWC f16 transpose + weight repack ----
__global__ __launch_bounds__(256) void transpose_prep(
    const float* __restrict__ x, unsigned short* __restrict__ xt,
    const float* __restrict__ w_dcn, const float* __restrict__ w_off,
    unsigned short* __restrict__ w_bf, unsigned short* __restrict__ wA)
{
    __shared__ unsigned tb[64 * 33];          // [pix][ch-pair], stride 33
    if (blockIdx.x >= B_ * 256) {             // weight-repack tail blocks
        int i = (blockIdx.x - B_ * 256) * 256 + threadIdx.x;
        if (i < 64 * CK_) {
            int o = i / CK_, r = i % CK_;
            int tap = r >> 6, c = r & 63;
            w_bf[i] = f2h(w_dcn[o * CK_ + c * 9 + tap]);
        } else {
            int j = i - 64 * CK_;             // 0 .. 32*576-1
            int o = j / CK_, r = j % CK_;
            int tap = r >> 6, c = r & 63;
            float v = (o < 27) ? w_off[o * CK_ + c * 9 + tap] : 0.f;
            wA[j] = f2h(v);
        }
        return;
    }
    int b = blockIdx.x >> 8;
    int pixbase = (blockIdx.x & 255) * 64;
    int t = threadIdx.x;
    #pragma unroll
    for (int i = 0; i < 2; ++i) {
        int idx = i * 256 + t;                // 0..511
        int cp = idx >> 4;                    // ch-pair 0..31
        int p4 = (idx & 15) * 4;              // pix 0..60 step 4
        const float* r0 = x + ((size_t)(b * C_) + 2 * cp    ) * HW_ + pixbase + p4;
        const float* r1 = x + ((size_t)(b * C_) + 2 * cp + 1) * HW_ + pixbase + p4;
        float4 f0 = *(const float4*)r0;
        float4 f1 = *(const float4*)r1;
        tb[(p4 + 0) * 33 + cp] = pkrtz(f0.x, f1.x);
        tb[(p4 + 1) * 33 + cp] = pkrtz(f0.y, f1.y);
        tb[(p4 + 2) * 33 + cp] = pkrtz(f0.z, f1.z);
        tb[(p4 + 3) * 33 + cp] = pkrtz(f0.w, f1.w);
    }
    __syncthreads();
    unsigned* xo = (unsigned*)xt + ((size_t)b * HW_ + pixbase) * 32;
    #pragma unroll
    for (int i = 0; i < 2; ++i) {
        int idx = i * 256 + t;
        int pix = idx >> 3, j = idx & 7;
        uint4 v;
        v.x = tb[pix * 33 + j * 4 + 0];
        v.y = tb[pix * 33 + j * 4 + 1];
        v.z = tb[pix * 33 + j * 4 + 2];
        v.w = tb[pix * 33 + j * 4 + 3];
        *(uint4*)(xo + pix * 32 + j * 4) = v;   // contiguous 1KB per wave-instr
    }
}

// ==== ROUND 9: ABLATION SPLIT (harness-safe, bit-exact) ====================
// All micro-theories (latency depth-1 async, occupancy, bank conflicts, XCD
// locality) individually falsified by A/B across r1-r8; bottom-up cycle
// accounting explains <40% of the 95us. Per methodology (Common-mistake #8):
// ablate before optimizing. Split the fused kernel into P1 (offset conv +
// scr prep) and P2 (gather+blend+GEMM) as separate dispatches -> rocprof
// reports per-phase dur/counters. scr round-trips through ws bit-exactly;
// math/order/layout unchanged -> output identical to dcn12 (95.3us verified).

// ---- dcn_p1: Phase A (offset conv via MFMA) + Phase 0 (scr prep) ----------
__global__ __launch_bounds__(256) void dcn_p1(
    const unsigned short* __restrict__ xt,    // f16 NHWC
    const unsigned short* __restrict__ wA,    // offset-conv weights [32][576] f16
    const float* __restrict__ b_off,
    uint4* __restrict__ scr_ws)               // [2048][576] {w.x, w.y, off, 0}
{
    __shared__ __align__(16) float om[27 * 65];   // 7 KB only -> high occupancy
    int tile = blockIdx.x;
    int b  = tile >> 8;
    int p0 = (tile & 255) * 64;
    int y  = p0 >> 7;
    int x0 = p0 & 127;
    int t  = threadIdx.x;
    int lane = t & 63, w = t >> 6;
    int m = lane & 15, q = lane >> 4;

    const unsigned short* xbr = xt + (size_t)(b * HW_) * 64;

    // ---- Phase A: verbatim from dcn12 ----
    {
        int o0c = (w & 1) * 16;
        int pxh = (w >> 1) * 32;

        f32x4 accc[2] = {};
        #pragma unroll
        for (int ky = 0; ky < 3; ++ky) {
            int yy = y + ky - 1;
            if (yy >= 0 && yy < H_) {
                const unsigned short* xr = xbr + (size_t)yy * W_ * 64;
                #pragma unroll
                for (int kx = 0; kx < 3; ++kx) {
                    int s2 = (ky * 3 + kx) * 2;
                    f16x8 A0 = *(const f16x8*)(wA + (o0c + m) * CK_ + s2 * 32 + q * 8);
                    f16x8 A1 = *(const f16x8*)(wA + (o0c + m) * CK_ + (s2 + 1) * 32 + q * 8);
                    #pragma unroll
                    for (int nt = 0; nt < 2; ++nt) {
                        int xbase = x0 + pxh + nt * 16;
                        int px = xbase + m + kx - 1;
                        f16x8 b0, b1;
                        bool ledge = (xbase == 0   && kx == 0);
                        bool redge = (xbase == 112 && kx == 2);
                        if (ledge || redge) {
                            int pc = min(max(px, 0), W_ - 1);
                            const unsigned short* p = xr + pc * 64 + q * 8;
                            b0 = *(const f16x8*)p;
                            b1 = *(const f16x8*)(p + 32);
                            if (px != pc) {
                                b0 = (f16x8){0,0,0,0,0,0,0,0};
                                b1 = (f16x8){0,0,0,0,0,0,0,0};
                            }
                        } else {
                            const unsigned short* p = xr + px * 64 + q * 8;
                            b0 = *(const f16x8*)p;
                            b1 = *(const f16x8*)(p + 32);
                        }
                        accc[nt] = __builtin_amdgcn_mfma_f32_16x16x32_f16(A0, b0, accc[nt], 0, 0, 0);
                        accc[nt] = __builtin_amdgcn_mfma_f32_16x16x32_f16(A1, b1, accc[nt], 0, 0, 0);
                    }
                }
            }
        }
        #pragma unroll
        for (int nt = 0; nt < 2; ++nt) {
            #pragma unroll
            for (int r = 0; r < 4; ++r) {
                int j = o0c + q * 4 + r;
                if (j < 27)
                    om[j * 65 + pxh + nt * 16 + m] = accc[nt][r] + b_off[j];
            }
        }
    }
    __syncthreads();

    // ---- Phase 0: verbatim math; emit scr record to workspace (coalesced) --
    uint4* srow = scr_ws + (size_t)tile * 576;
    for (int i = t; i < 576; i += 256) {
        int k = i >> 6, sp = i & 63;
        float dy = om[(2 * k)     * 65 + sp];
        float dx = om[(2 * k + 1) * 65 + sp];
        float mk = 1.f / (1.f + __expf(-om[(18 + k) * 65 + sp]));
        float py = dy + (float)(y - 1 + k / 3);
        float px = dx + (float)(x0 + sp - 1 + k % 3);
        float fy = floorf(py), fx = floorf(px);
        int iy = (int)fy, ix = (int)fx;
        float ay = py - fy, ax = px - fx;
        float wy0 = (iy >= 0  && iy < H_)     ? (1.f - ay) : 0.f;
        float wy1 = (iy >= -1 && iy < H_ - 1) ? ay         : 0.f;
        float wx0 = (ix >= 0  && ix < W_)     ? (1.f - ax) : 0.f;
        float wx1 = (ix >= -1 && ix < W_ - 1) ? ax         : 0.f;
        int iy0 = min(max(iy, 0), H_ - 1);
        int iy1 = min(max(iy + 1, 0), H_ - 1);
        int ix0 = min(max(ix, 0), W_ - 1);
        int ix1 = min(max(ix + 1, 0), W_ - 1);
        float w00 = wy0*wx0*mk, w01 = wy0*wx1*mk, w10 = wy1*wx0*mk, w11 = wy1*wx1*mk;
        uint4 rec;
        rec.x = pkrtz(w00, w01);              // lo=w00 hi=w01
        rec.y = pkrtz(w10, w11);              // lo=w10 hi=w11
        int off00 = (iy0 * W_ + ix0) * 128;   // bytes (64ch * 2B f16)
        rec.z = (unsigned)(off00 | ((ix1 != ix0) << 22) | ((iy1 != iy0) << 23));
        rec.w = 0;
        srow[i] = rec;
    }
}

// ---- dcn_p2: scr staging + Phase B (gather/blend/GEMM) verbatim -----------
#define SSTR4 400     // sS row stride bytes, 16B aligned
__global__ __launch_bounds__(256, 4) void dcn_p2(
    const unsigned short* __restrict__ xt,    // f16 NHWC
    const unsigned short* __restrict__ w_bf,  // dcn weights [64][576] f16
    const uint4* __restrict__ scr_ws,
    float* __restrict__ out)
{
    __shared__ __align__(16) unsigned char sS[64 * SSTR4];  // 25600 B
    __shared__ uint2 scr_w[576];
    __shared__ int   scr_o[576];

    int tile = blockIdx.x;
    int b  = tile >> 8;
    int p0 = (tile & 255) * 64;
    int t  = threadIdx.x;
    int lane = t & 63, w = t >> 6;
    int m = lane & 15, q = lane >> 4;

    const unsigned short* xbr = xt + (size_t)(b * HW_) * 64;

    // stage scr from ws (coalesced uint4 reads, L3-hot)
    const uint4* srow = scr_ws + (size_t)tile * 576;
    for (int i = t; i < 576; i += 256) {
        uint4 rec = srow[i];
        scr_w[i] = (uint2){rec.x, rec.y};
        scr_o[i] = (int)rec.z;
    }
    int o0 = w * 16;
    __syncthreads();

    // ---- Phase B: verbatim from dcn12 (95.3us verified) ----
    int cq = lane & 7;
    int g  = lane >> 3;
    const unsigned char* xb = (const unsigned char*)xbr;
    f32x4 acc[4] = {};
    int piB = w * 8 + g;

    uint2 wA_, wB_; int pB_;
    uint4 a00, a01, a10, a11;
    {
        wA_ = scr_w[piB];      int oo = scr_o[piB];
        wB_ = scr_w[piB + 32]; pB_ = scr_o[piB + 32];
        const unsigned char* a0 = xb + (oo & 0x3FFFFF) + cq * 16;
        int dxb = (oo >> 15) & 128;
        int dyb = (oo >> 9)  & 16384;
        a00 = *(const uint4*)(a0);
        a01 = *(const uint4*)(a0 + dxb);
        a10 = *(const uint4*)(a0 + dyb);
        a11 = *(const uint4*)(a0 + dyb + dxb);
    }

    #pragma unroll
    for (int chunk = 0; chunk < 3; ++chunk) {
        #pragma unroll
        for (int it6 = 0; it6 < 6; ++it6) {
            const int k = chunk * 6 + it6;
            uint2 wC_ = {}; int pC_ = 0;
            if (k + 2 < 18) {
                int P = piB + (k + 2) * 32;
                wC_ = scr_w[P]; pC_ = scr_o[P];
            }
            uint4 n00 = {}, n01 = {}, n10 = {}, n11 = {};
            if (k + 1 < 18) {
                const unsigned char* a0 = xb + (pB_ & 0x3FFFFF) + cq * 16;
                int dxb = (pB_ >> 15) & 128;
                int dyb = (pB_ >> 9)  & 16384;
                n00 = *(const uint4*)(a0);
                n01 = *(const uint4*)(a0 + dxb);
                n10 = *(const uint4*)(a0 + dyb);
                n11 = *(const uint4*)(a0 + dyb + dxb);
            }
            h2 w00 = bcast_lo(wA_.x), w01 = bcast_hi(wA_.x);
            h2 w10 = bcast_lo(wA_.y), w11 = bcast_hi(wA_.y);
            uint4 o4; h2 r;
            r = w00*u2h(a00.x) + w01*u2h(a01.x) + w10*u2h(a10.x) + w11*u2h(a11.x); o4.x = h2u(r);
            r = w00*u2h(a00.y) + w01*u2h(a01.y) + w10*u2h(a10.y) + w11*u2h(a11.y); o4.y = h2u(r);
            r = w00*u2h(a00.z) + w01*u2h(a01.z) + w10*u2h(a10.z) + w11*u2h(a11.z); o4.z = h2u(r);
            r = w00*u2h(a00.w) + w01*u2h(a01.w) + w10*u2h(a10.w) + w11*u2h(a11.w); o4.w = h2u(r);
            int sp  = (piB + (k & 1) * 32) & 63;
            int ktl = it6 >> 1;
            *(uint4*)&sS[sp * SSTR4 + ktl * 128 + cq * 16] = o4;
            wA_ = wB_; wB_ = wC_; pB_ = pC_;
            a00 = n00; a01 = n01; a10 = n10; a11 = n11;
        }
        f16x8 Af[6];
        #pragma unroll
        for (int s = 0; s < 6; ++s)
            Af[s] = *(const f16x8*)(w_bf + (o0 + m) * CK_ + (chunk * 6 + s) * 32 + q * 8);
        __syncthreads();

        #pragma unroll
        for (int s = 0; s < 6; ++s) {
            #pragma unroll
            for (int nt = 0; nt < 4; ++nt) {
                f16x8 bb = *(const f16x8*)&sS[(nt * 16 + m) * SSTR4 + s * 64 + q * 16];
                acc[nt] = __builtin_amdgcn_mfma_f32_16x16x32_f16(Af[s], bb, acc[nt], 0, 0, 0);
            }
        }
        __syncthreads();
    }

    #pragma unroll
    for (int nt = 0; nt < 4; ++nt) {
        #pragma unroll
        for (int r = 0; r < 4; ++r) {
            int o = o0 + q * 4 + r;
            out[((size_t)(b * CO_ + o)) * HW_ + p0 + nt * 16 + m] = acc[nt][r];
        }
    }
}

extern "C" void kernel_launch(void* const* d_in, const int* in_sizes, int n_in,
                              void* d_out, int out_size, void* d_ws, size_t ws_size,
                              hipStream_t stream)
{
    const float* x     = (const float*)d_in[0];
    const float* w_off = (const float*)d_in[1];
    const float* b_off = (const float*)d_in[2];
    const float* w_dcn = (const float*)d_in[3];
    float* out = (float*)d_out;

    unsigned short* xt   = (unsigned short*)d_ws;                // 16.8 MB
    unsigned short* w_bf = xt + (size_t)B_ * HW_ * 64;           // 73.7 KB
    unsigned short* wA   = w_bf + 64 * CK_;                      // 36.9 KB
    uint4* scr_ws = (uint4*)(wA + 32 * CK_);                     // 18.9 MB (16B-aligned)

    transpose_prep<<<B_ * 256 + 216, 256, 0, stream>>>(x, xt, w_dcn, w_off, w_bf, wA);
    dcn_p1<<<B_ * 256, 256, 0, stream>>>(xt, wA, b_off, scr_ws);
    dcn_p2<<<B_ * 256, 256, 0, stream>>>(xt, w_bf, scr_ws, out);
}

// Round 10
// 161.113 us; speedup vs baseline: 1.1248x; 1.1248x over previous
//
#include <hip/hip_runtime.h>
#include <math.h>

#define B_  8
#define C_  64
#define H_  128
#define W_  128
#define KK_ 9
#define CO_ 64
#define HW_ (H_*W_)
#define CK_ 576

typedef _Float16 f16x8 __attribute__((ext_vector_type(8)));
typedef _Float16 h2    __attribute__((ext_vector_type(2)));
typedef __attribute__((ext_vector_type(4))) float f32x4;

__device__ inline unsigned pkrtz(float a, float b){
    auto v = __builtin_amdgcn_cvt_pkrtz(a, b);   // __fp16x2 on this toolchain
    union{decltype(v) h; unsigned u;} c; c.h = v; return c.u;
}
__device__ inline h2 u2h(unsigned u){ union{unsigned x; h2 h;} c; c.x = u; return c.h; }
__device__ inline unsigned h2u(h2 v){ union{h2 h; unsigned u;} c; c.h = v; return c.u; }
__device__ inline unsigned short f2h(float f){
    _Float16 h = (_Float16)f;
    union{_Float16 h; unsigned short s;} c; c.h = h; return c.s;
}
// broadcast lo/hi f16 of a dword into both halves (1 v_perm_b32 each)
__device__ inline h2 bcast_lo(unsigned u){ return u2h(__builtin_amdgcn_perm(u, u, 0x01000100)); }
__device__ inline h2 bcast_hi(unsigned u){ return u2h(__builtin_amdgcn_perm(u, u, 0x03020302)); }

// ---- transpose_prep: fused x NCHW->NHWC f16 transpose + weight repack ----
__global__ __launch_bounds__(256) void transpose_prep(
    const float* __restrict__ x, unsigned short* __restrict__ xt,
    const float* __restrict__ w_dcn, const float* __restrict__ w_off,
    unsigned short* __restrict__ w_bf, unsigned short* __restrict__ wA)
{
    __shared__ unsigned tb[64 * 33];          // [pix][ch-pair], stride 33
    if (blockIdx.x >= B_ * 256) {             // weight-repack tail blocks
        int i = (blockIdx.x - B_ * 256) * 256 + threadIdx.x;
        if (i < 64 * CK_) {
            int o = i / CK_, r = i % CK_;
            int tap = r >> 6, c = r & 63;
            w_bf[i] = f2h(w_dcn[o * CK_ + c * 9 + tap]);
        } else {
            int j = i - 64 * CK_;             // 0 .. 32*576-1
            int o = j / CK_, r = j % CK_;
            int tap = r >> 6, c = r & 63;
            float v = (o < 27) ? w_off[o * CK_ + c * 9 + tap] : 0.f;
            wA[j] = f2h(v);
        }
        return;
    }
    int b = blockIdx.x >> 8;
    int pixbase = (blockIdx.x & 255) * 64;
    int t = threadIdx.x;
    #pragma unroll
    for (int i = 0; i < 2; ++i) {
        int idx = i * 256 + t;                // 0..511
        int cp = idx >> 4;                    // ch-pair 0..31
        int p4 = (idx & 15) * 4;              // pix 0..60 step 4
        const float* r0 = x + ((size_t)(b * C_) + 2 * cp    ) * HW_ + pixbase + p4;
        const float* r1 = x + ((size_t)(b * C_) + 2 * cp + 1) * HW_ + pixbase + p4;
        float4 f0 = *(const float4*)r0;
        float4 f1 = *(const float4*)r1;
        tb[(p4 + 0) * 33 + cp] = pkrtz(f0.x, f1.x);
        tb[(p4 + 1) * 33 + cp] = pkrtz(f0.y, f1.y);
        tb[(p4 + 2) * 33 + cp] = pkrtz(f0.z, f1.z);
        tb[(p4 + 3) * 33 + cp] = pkrtz(f0.w, f1.w);
    }
    __syncthreads();
    unsigned* xo = (unsigned*)xt + ((size_t)b * HW_ + pixbase) * 32;
    #pragma unroll
    for (int i = 0; i < 2; ++i) {
        int idx = i * 256 + t;
        int pix = idx >> 3, j = idx & 7;
        uint4 v;
        v.x = tb[pix * 33 + j * 4 + 0];
        v.y = tb[pix * 33 + j * 4 + 1];
        v.z = tb[pix * 33 + j * 4 + 2];
        v.w = tb[pix * 33 + j * 4 + 3];
        *(uint4*)(xo + pix * 32 + j * 4) = v;   // contiguous 1KB per wave-instr
    }
}

// ==== ROUND 10: P1 halo-staging (ablation said P1=55.6us dominates) ========
// Diagnosis from r9 split: Phase A re-reads xt per-tap (442 MB total, 9x
// redundancy) through L3 (~8 TB/s effective) -> P1 is an L3-stream kernel
// with 3% MfmaUtil. Fix: stage the 3-row x 66-col x 64ch halo in LDS ONCE
// per block (25.3 KB, one coalesced stream), taps read ds_read_b128.
// Pixel stride padded 128->144B: bank = 4*(px+q) mod 32 -> 2-way max (free).
// Out-of-range rows/cols stage ZEROS == original skip/clamp-zero semantics
// (MFMA with zero B adds exactly 0; accumulation order unchanged -> bit-exact).
// P2 untouched (attribution).

#define PXB 144                               // bytes per staged pixel
#define ROWB (66 * PXB)                       // 9504 B per staged row

// ---- dcn_p1b: halo-staged Phase A + Phase 0 -------------------------------
__global__ __launch_bounds__(256) void dcn_p1b(
    const unsigned short* __restrict__ xt,    // f16 NHWC
    const unsigned short* __restrict__ wA,    // offset-conv weights [32][576] f16
    const float* __restrict__ b_off,
    uint4* __restrict__ scr_ws)               // [2048][576] {w.x, w.y, off, 0}
{
    __shared__ __align__(16) unsigned char xrow[3 * ROWB];  // 28512 B
    float* om = (float*)xrow;                 // aliased after Phase A (barrier)

    int tile = blockIdx.x;
    int b  = tile >> 8;
    int p0 = (tile & 255) * 64;
    int y  = p0 >> 7;
    int x0 = p0 & 127;
    int t  = threadIdx.x;
    int lane = t & 63, w = t >> 6;
    int m = lane & 15, q = lane >> 4;

    const unsigned short* xbr = xt + (size_t)(b * HW_) * 64;

    // ---- stage halo: rows y-1..y+1, cols x0-1..x0+64, zeros out of range ---
    for (int i = t; i < 3 * 66 * 8; i += 256) {
        int r = i / 528;                      // 0..2
        int rem = i - r * 528;
        int c = rem >> 3;                     // 0..65
        int g = rem & 7;                      // 16B chunk within pixel
        int yy = y - 1 + r;
        int xx = x0 - 1 + c;
        uint4 v = {0, 0, 0, 0};
        if (yy >= 0 && yy < H_ && xx >= 0 && xx < W_)
            v = *(const uint4*)(xbr + ((size_t)yy * W_ + xx) * 64 + g * 8);
        *(uint4*)(xrow + r * ROWB + c * PXB + g * 16) = v;
    }
    __syncthreads();

    // ---- Phase A: offset conv; B-operand from LDS ----
    {
        int o0c = (w & 1) * 16;
        int pxh = (w >> 1) * 32;

        f32x4 accc[2] = {};
        #pragma unroll
        for (int ky = 0; ky < 3; ++ky) {
            #pragma unroll
            for (int kx = 0; kx < 3; ++kx) {
                int s2 = (ky * 3 + kx) * 2;
                f16x8 A0 = *(const f16x8*)(wA + (o0c + m) * CK_ + s2 * 32 + q * 8);
                f16x8 A1 = *(const f16x8*)(wA + (o0c + m) * CK_ + (s2 + 1) * 32 + q * 8);
                #pragma unroll
                for (int nt = 0; nt < 2; ++nt) {
                    int c = pxh + nt * 16 + m + kx;   // staged col (0..65)
                    const unsigned char* p = xrow + ky * ROWB + c * PXB + q * 16;
                    f16x8 b0 = *(const f16x8*)p;
                    f16x8 b1 = *(const f16x8*)(p + 64);
                    accc[nt] = __builtin_amdgcn_mfma_f32_16x16x32_f16(A0, b0, accc[nt], 0, 0, 0);
                    accc[nt] = __builtin_amdgcn_mfma_f32_16x16x32_f16(A1, b1, accc[nt], 0, 0, 0);
                }
            }
        }
        __syncthreads();      // staging region about to be overwritten by om
        #pragma unroll
        for (int nt = 0; nt < 2; ++nt) {
            #pragma unroll
            for (int r = 0; r < 4; ++r) {
                int j = o0c + q * 4 + r;
                if (j < 27)
                    om[j * 65 + pxh + nt * 16 + m] = accc[nt][r] + b_off[j];
            }
        }
    }
    __syncthreads();

    // ---- Phase 0: verbatim math; emit scr record to workspace (coalesced) --
    uint4* srow = scr_ws + (size_t)tile * 576;
    for (int i = t; i < 576; i += 256) {
        int k = i >> 6, sp = i & 63;
        float dy = om[(2 * k)     * 65 + sp];
        float dx = om[(2 * k + 1) * 65 + sp];
        float mk = 1.f / (1.f + __expf(-om[(18 + k) * 65 + sp]));
        float py = dy + (float)(y - 1 + k / 3);
        float px = dx + (float)(x0 + sp - 1 + k % 3);
        float fy = floorf(py), fx = floorf(px);
        int iy = (int)fy, ix = (int)fx;
        float ay = py - fy, ax = px - fx;
        float wy0 = (iy >= 0  && iy < H_)     ? (1.f - ay) : 0.f;
        float wy1 = (iy >= -1 && iy < H_ - 1) ? ay         : 0.f;
        float wx0 = (ix >= 0  && ix < W_)     ? (1.f - ax) : 0.f;
        float wx1 = (ix >= -1 && ix < W_ - 1) ? ax         : 0.f;
        int iy0 = min(max(iy, 0), H_ - 1);
        int iy1 = min(max(iy + 1, 0), H_ - 1);
        int ix0 = min(max(ix, 0), W_ - 1);
        int ix1 = min(max(ix + 1, 0), W_ - 1);
        float w00 = wy0*wx0*mk, w01 = wy0*wx1*mk, w10 = wy1*wx0*mk, w11 = wy1*wx1*mk;
        uint4 rec;
        rec.x = pkrtz(w00, w01);              // lo=w00 hi=w01
        rec.y = pkrtz(w10, w11);              // lo=w10 hi=w11
        int off00 = (iy0 * W_ + ix0) * 128;   // bytes (64ch * 2B f16)
        rec.z = (unsigned)(off00 | ((ix1 != ix0) << 22) | ((iy1 != iy0) << 23));
        rec.w = 0;
        srow[i] = rec;
    }
}

// ---- dcn_p2: scr staging + Phase B (gather/blend/GEMM) verbatim -----------
#define SSTR4 400     // sS row stride bytes, 16B aligned
__global__ __launch_bounds__(256, 4) void dcn_p2(
    const unsigned short* __restrict__ xt,    // f16 NHWC
    const unsigned short* __restrict__ w_bf,  // dcn weights [64][576] f16
    const uint4* __restrict__ scr_ws,
    float* __restrict__ out)
{
    __shared__ __align__(16) unsigned char sS[64 * SSTR4];  // 25600 B
    __shared__ uint2 scr_w[576];
    __shared__ int   scr_o[576];

    int tile = blockIdx.x;
    int b  = tile >> 8;
    int p0 = (tile & 255) * 64;
    int t  = threadIdx.x;
    int lane = t & 63, w = t >> 6;
    int m = lane & 15, q = lane >> 4;

    const unsigned short* xbr = xt + (size_t)(b * HW_) * 64;

    // stage scr from ws (coalesced uint4 reads, L3-hot)
    const uint4* srow = scr_ws + (size_t)tile * 576;
    for (int i = t; i < 576; i += 256) {
        uint4 rec = srow[i];
        scr_w[i] = (uint2){rec.x, rec.y};
        scr_o[i] = (int)rec.z;
    }
    int o0 = w * 16;
    __syncthreads();

    // ---- Phase B: verbatim from dcn12 (95.3us verified) ----
    int cq = lane & 7;
    int g  = lane >> 3;
    const unsigned char* xb = (const unsigned char*)xbr;
    f32x4 acc[4] = {};
    int piB = w * 8 + g;

    uint2 wA_, wB_; int pB_;
    uint4 a00, a01, a10, a11;
    {
        wA_ = scr_w[piB];      int oo = scr_o[piB];
        wB_ = scr_w[piB + 32]; pB_ = scr_o[piB + 32];
        const unsigned char* a0 = xb + (oo & 0x3FFFFF) + cq * 16;
        int dxb = (oo >> 15) & 128;
        int dyb = (oo >> 9)  & 16384;
        a00 = *(const uint4*)(a0);
        a01 = *(const uint4*)(a0 + dxb);
        a10 = *(const uint4*)(a0 + dyb);
        a11 = *(const uint4*)(a0 + dyb + dxb);
    }

    #pragma unroll
    for (int chunk = 0; chunk < 3; ++chunk) {
        #pragma unroll
        for (int it6 = 0; it6 < 6; ++it6) {
            const int k = chunk * 6 + it6;
            uint2 wC_ = {}; int pC_ = 0;
            if (k + 2 < 18) {
                int P = piB + (k + 2) * 32;
                wC_ = scr_w[P]; pC_ = scr_o[P];
            }
            uint4 n00 = {}, n01 = {}, n10 = {}, n11 = {};
            if (k + 1 < 18) {
                const unsigned char* a0 = xb + (pB_ & 0x3FFFFF) + cq * 16;
                int dxb = (pB_ >> 15) & 128;
                int dyb = (pB_ >> 9)  & 16384;
                n00 = *(const uint4*)(a0);
                n01 = *(const uint4*)(a0 + dxb);
                n10 = *(const uint4*)(a0 + dyb);
                n11 = *(const uint4*)(a0 + dyb + dxb);
            }
            h2 w00 = bcast_lo(wA_.x), w01 = bcast_hi(wA_.x);
            h2 w10 = bcast_lo(wA_.y), w11 = bcast_hi(wA_.y);
            uint4 o4; h2 r;
            r = w00*u2h(a00.x) + w01*u2h(a01.x) + w10*u2h(a10.x) + w11*u2h(a11.x); o4.x = h2u(r);
            r = w00*u2h(a00.y) + w01*u2h(a01.y) + w10*u2h(a10.y) + w11*u2h(a11.y); o4.y = h2u(r);
            r = w00*u2h(a00.z) + w01*u2h(a01.z) + w10*u2h(a10.z) + w11*u2h(a11.z); o4.z = h2u(r);
            r = w00*u2h(a00.w) + w01*u2h(a01.w) + w10*u2h(a10.w) + w11*u2h(a11.w); o4.w = h2u(r);
            int sp  = (piB + (k & 1) * 32) & 63;
            int ktl = it6 >> 1;
            *(uint4*)&sS[sp * SSTR4 + ktl * 128 + cq * 16] = o4;
            wA_ = wB_; wB_ = wC_; pB_ = pC_;
            a00 = n00; a01 = n01; a10 = n10; a11 = n11;
        }
        f16x8 Af[6];
        #pragma unroll
        for (int s = 0; s < 6; ++s)
            Af[s] = *(const f16x8*)(w_bf + (o0 + m) * CK_ + (chunk * 6 + s) * 32 + q * 8);
        __syncthreads();

        #pragma unroll
        for (int s = 0; s < 6; ++s) {
            #pragma unroll
            for (int nt = 0; nt < 4; ++nt) {
                f16x8 bb = *(const f16x8*)&sS[(nt * 16 + m) * SSTR4 + s * 64 + q * 16];
                acc[nt] = __builtin_amdgcn_mfma_f32_16x16x32_f16(Af[s], bb, acc[nt], 0, 0, 0);
            }
        }
        __syncthreads();
    }

    #pragma unroll
    for (int nt = 0; nt < 4; ++nt) {
        #pragma unroll
        for (int r = 0; r < 4; ++r) {
            int o = o0 + q * 4 + r;
            out[((size_t)(b * CO_ + o)) * HW_ + p0 + nt * 16 + m] = acc[nt][r];
        }
    }
}

extern "C" void kernel_launch(void* const* d_in, const int* in_sizes, int n_in,
                              void* d_out, int out_size, void* d_ws, size_t ws_size,
                              hipStream_t stream)
{
    const float* x     = (const float*)d_in[0];
    const float* w_off = (const float*)d_in[1];
    const float* b_off = (const float*)d_in[2];
    const float* w_dcn = (const float*)d_in[3];
    float* out = (float*)d_out;

    unsigned short* xt   = (unsigned short*)d_ws;                // 16.8 MB
    unsigned short* w_bf = xt + (size_t)B_ * HW_ * 64;           // 73.7 KB
    unsigned short* wA   = w_bf + 64 * CK_;                      // 36.9 KB
    uint4* scr_ws = (uint4*)(wA + 32 * CK_);                     // 18.9 MB (16B-aligned)

    transpose_prep<<<B_ * 256 + 216, 256, 0, stream>>>(x, xt, w_dcn, w_off, w_bf, wA);
    dcn_p1b<<<B_ * 256, 256, 0, stream>>>(xt, wA, b_off, scr_ws);
    dcn_p2<<<B_ * 256, 256, 0, stream>>>(xt, w_bf, scr_ws, out);
}

// Round 11
// 145.899 us; speedup vs baseline: 1.2421x; 1.1043x over previous
//
#include <hip/hip_runtime.h>
#include <math.h>

#define B_  8
#define C_  64
#define H_  128
#define W_  128
#define KK_ 9
#define CO_ 64
#define HW_ (H_*W_)
#define CK_ 576

typedef _Float16 f16x8 __attribute__((ext_vector_type(8)));
typedef _Float16 h2    __attribute__((ext_vector_type(2)));
typedef __attribute__((ext_vector_type(4))) float f32x4;

__device__ inline unsigned pkrtz(float a, float b){
    auto v = __builtin_amdgcn_cvt_pkrtz(a, b);   // __fp16x2 on this toolchain
    union{decltype(v) h; unsigned u;} c; c.h = v; return c.u;
}
__device__ inline h2 u2h(unsigned u){ union{unsigned x; h2 h;} c; c.x = u; return c.h; }
__device__ inline unsigned h2u(h2 v){ union{h2 h; unsigned u;} c; c.h = v; return c.u; }
__device__ inline unsigned short f2h(float f){
    _Float16 h = (_Float16)f;
    union{_Float16 h; unsigned short s;} c; c.h = h; return c.s;
}
// broadcast lo/hi f16 of a dword into both halves (1 v_perm_b32 each)
__device__ inline h2 bcast_lo(unsigned u){ return u2h(__builtin_amdgcn_perm(u, u, 0x01000100)); }
__device__ inline h2 bcast_hi(unsigned u){ return u2h(__builtin_amdgcn_perm(u, u, 0x03020302)); }

// ---- transpose_prep: fused x NCHW->NHWC f16 transpose + weight repack ----
__global__ __launch_bounds__(256) void transpose_prep(
    const float* __restrict__ x, unsigned short* __restrict__ xt,
    const float* __restrict__ w_dcn, const float* __restrict__ w_off,
    unsigned short* __restrict__ w_bf, unsigned short* __restrict__ wA)
{
    __shared__ unsigned tb[64 * 33];          // [pix][ch-pair], stride 33
    if (blockIdx.x >= B_ * 256) {             // weight-repack tail blocks
        int i = (blockIdx.x - B_ * 256) * 256 + threadIdx.x;
        if (i < 64 * CK_) {
            int o = i / CK_, r = i % CK_;
            int tap = r >> 6, c = r & 63;
            w_bf[i] = f2h(w_dcn[o * CK_ + c * 9 + tap]);
        } else {
            int j = i - 64 * CK_;             // 0 .. 32*576-1
            int o = j / CK_, r = j % CK_;
            int tap = r >> 6, c = r & 63;
            float v = (o < 27) ? w_off[o * CK_ + c * 9 + tap] : 0.f;
            wA[j] = f2h(v);
        }
        return;
    }
    int b = blockIdx.x >> 8;
    int pixbase = (blockIdx.x & 255) * 64;
    int t = threadIdx.x;
    #pragma unroll
    for (int i = 0; i < 2; ++i) {
        int idx = i * 256 + t;                // 0..511
        int cp = idx >> 4;                    // ch-pair 0..31
        int p4 = (idx & 15) * 4;              // pix 0..60 step 4
        const float* r0 = x + ((size_t)(b * C_) + 2 * cp    ) * HW_ + pixbase + p4;
        const float* r1 = x + ((size_t)(b * C_) + 2 * cp + 1) * HW_ + pixbase + p4;
        float4 f0 = *(const float4*)r0;
        float4 f1 = *(const float4*)r1;
        tb[(p4 + 0) * 33 + cp] = pkrtz(f0.x, f1.x);
        tb[(p4 + 1) * 33 + cp] = pkrtz(f0.y, f1.y);
        tb[(p4 + 2) * 33 + cp] = pkrtz(f0.z, f1.z);
        tb[(p4 + 3) * 33 + cp] = pkrtz(f0.w, f1.w);
    }
    __syncthreads();
    unsigned* xo = (unsigned*)xt + ((size_t)b * HW_ + pixbase) * 32;
    #pragma unroll
    for (int i = 0; i < 2; ++i) {
        int idx = i * 256 + t;
        int pix = idx >> 3, j = idx & 7;
        uint4 v;
        v.x = tb[pix * 33 + j * 4 + 0];
        v.y = tb[pix * 33 + j * 4 + 1];
        v.z = tb[pix * 33 + j * 4 + 2];
        v.w = tb[pix * 33 + j * 4 + 3];
        *(uint4*)(xo + pix * 32 + j * 4) = v;   // contiguous 1KB per wave-instr
    }
}

// ==== ROUND 11: re-fuse P1+P2 with halo staging (attribution complete) =====
// r9/r10 established: P1 was L3-stream bound (halo staging fixed it, 55.6->
// ~22us); P2 is a balanced L1/LDS/VALU kernel (~49us); fixed harness overhead
// ~80us. Fusing recovers the 38MB scr round trip, one full device drain, and
// inter-block phase overlap (P1-phase L3 streaming || P2-phase L1/LDS/VALU).
// LDS: halo 28512B (aliased by om, then by sS) + scr 6912B live = 35424B
// -> 4 blocks/CU. All phases verbatim from harness-passed kernels -> bit-exact.

#define PXB 144                               // bytes per staged halo pixel
#define ROWB (66 * PXB)                       // 9504 B per staged row
#define SSTR4 400                             // sS row stride bytes

__global__ __launch_bounds__(256, 4) void dcn15(
    const unsigned short* __restrict__ xt,    // f16 NHWC
    const unsigned short* __restrict__ wA,    // offset-conv weights [32][576] f16
    const float* __restrict__ b_off,
    const unsigned short* __restrict__ w_bf,  // dcn weights [64][576] f16
    float* __restrict__ out)
{
    __shared__ __align__(16) unsigned char xrow[3 * ROWB];  // 28512 B
    __shared__ uint2 scr_w[576];              // 4608 B, live through Phase B
    __shared__ int   scr_o[576];              // 2304 B
    float* om = (float*)xrow;                 // alias after Phase A (barrier)
    unsigned char* sS = xrow;                 // alias in Phase B (25600<=28512)

    int tile = blockIdx.x;
    int b  = tile >> 8;
    int p0 = (tile & 255) * 64;
    int y  = p0 >> 7;
    int x0 = p0 & 127;
    int t  = threadIdx.x;
    int lane = t & 63, w = t >> 6;
    int m = lane & 15, q = lane >> 4;

    const unsigned short* xbr = xt + (size_t)(b * HW_) * 64;

    // ---- stage halo: rows y-1..y+1, cols x0-1..x0+64, zeros out of range ---
    for (int i = t; i < 3 * 66 * 8; i += 256) {
        int r = i / 528;                      // 0..2
        int rem = i - r * 528;
        int c = rem >> 3;                     // 0..65
        int g = rem & 7;                      // 16B chunk within pixel
        int yy = y - 1 + r;
        int xx = x0 - 1 + c;
        uint4 v = {0, 0, 0, 0};
        if (yy >= 0 && yy < H_ && xx >= 0 && xx < W_)
            v = *(const uint4*)(xbr + ((size_t)yy * W_ + xx) * 64 + g * 8);
        *(uint4*)(xrow + r * ROWB + c * PXB + g * 16) = v;
    }
    __syncthreads();

    // ---- Phase A: offset conv; B-operand from LDS halo (r10-verified) ------
    {
        int o0c = (w & 1) * 16;
        int pxh = (w >> 1) * 32;

        f32x4 accc[2] = {};
        #pragma unroll
        for (int ky = 0; ky < 3; ++ky) {
            #pragma unroll
            for (int kx = 0; kx < 3; ++kx) {
                int s2 = (ky * 3 + kx) * 2;
                f16x8 A0 = *(const f16x8*)(wA + (o0c + m) * CK_ + s2 * 32 + q * 8);
                f16x8 A1 = *(const f16x8*)(wA + (o0c + m) * CK_ + (s2 + 1) * 32 + q * 8);
                #pragma unroll
                for (int nt = 0; nt < 2; ++nt) {
                    int c = pxh + nt * 16 + m + kx;   // staged col (0..65)
                    const unsigned char* p = xrow + ky * ROWB + c * PXB + q * 16;
                    f16x8 b0 = *(const f16x8*)p;
                    f16x8 b1 = *(const f16x8*)(p + 64);
                    accc[nt] = __builtin_amdgcn_mfma_f32_16x16x32_f16(A0, b0, accc[nt], 0, 0, 0);
                    accc[nt] = __builtin_amdgcn_mfma_f32_16x16x32_f16(A1, b1, accc[nt], 0, 0, 0);
                }
            }
        }
        __syncthreads();      // halo dead; om about to overwrite the region
        #pragma unroll
        for (int nt = 0; nt < 2; ++nt) {
            #pragma unroll
            for (int r = 0; r < 4; ++r) {
                int j = o0c + q * 4 + r;
                if (j < 27)
                    om[j * 65 + pxh + nt * 16 + m] = accc[nt][r] + b_off[j];
            }
        }
    }
    __syncthreads();

    // ---- Phase 0: offsets -> 4xf16 weights + packed offsets (LDS scr) ------
    for (int i = t; i < 576; i += 256) {
        int k = i >> 6, sp = i & 63;
        float dy = om[(2 * k)     * 65 + sp];
        float dx = om[(2 * k + 1) * 65 + sp];
        float mk = 1.f / (1.f + __expf(-om[(18 + k) * 65 + sp]));
        float py = dy + (float)(y - 1 + k / 3);
        float px = dx + (float)(x0 + sp - 1 + k % 3);
        float fy = floorf(py), fx = floorf(px);
        int iy = (int)fy, ix = (int)fx;
        float ay = py - fy, ax = px - fx;
        float wy0 = (iy >= 0  && iy < H_)     ? (1.f - ay) : 0.f;
        float wy1 = (iy >= -1 && iy < H_ - 1) ? ay         : 0.f;
        float wx0 = (ix >= 0  && ix < W_)     ? (1.f - ax) : 0.f;
        float wx1 = (ix >= -1 && ix < W_ - 1) ? ax         : 0.f;
        int iy0 = min(max(iy, 0), H_ - 1);
        int iy1 = min(max(iy + 1, 0), H_ - 1);
        int ix0 = min(max(ix, 0), W_ - 1);
        int ix1 = min(max(ix + 1, 0), W_ - 1);
        float w00 = wy0*wx0*mk, w01 = wy0*wx1*mk, w10 = wy1*wx0*mk, w11 = wy1*wx1*mk;
        uint2 wv;
        wv.x = pkrtz(w00, w01);               // lo=w00 hi=w01
        wv.y = pkrtz(w10, w11);               // lo=w10 hi=w11
        scr_w[i] = wv;
        int off00 = (iy0 * W_ + ix0) * 128;   // bytes (64ch * 2B f16)
        scr_o[i] = off00 | ((ix1 != ix0) << 22) | ((iy1 != iy0) << 23);
    }

    int o0 = w * 16;
    __syncthreads();        // scr ready; om region (sS) now free

    // ---- Phase B: verbatim dcn12 (95.3us-verified) rolling pipeline --------
    int cq = lane & 7;
    int g  = lane >> 3;
    const unsigned char* xb = (const unsigned char*)xbr;
    f32x4 acc[4] = {};
    int piB = w * 8 + g;

    uint2 wA_, wB_; int pB_;
    uint4 a00, a01, a10, a11;
    {
        wA_ = scr_w[piB];      int oo = scr_o[piB];
        wB_ = scr_w[piB + 32]; pB_ = scr_o[piB + 32];
        const unsigned char* a0 = xb + (oo & 0x3FFFFF) + cq * 16;
        int dxb = (oo >> 15) & 128;
        int dyb = (oo >> 9)  & 16384;
        a00 = *(const uint4*)(a0);
        a01 = *(const uint4*)(a0 + dxb);
        a10 = *(const uint4*)(a0 + dyb);
        a11 = *(const uint4*)(a0 + dyb + dxb);
    }

    #pragma unroll
    for (int chunk = 0; chunk < 3; ++chunk) {
        #pragma unroll
        for (int it6 = 0; it6 < 6; ++it6) {
            const int k = chunk * 6 + it6;
            uint2 wC_ = {}; int pC_ = 0;
            if (k + 2 < 18) {
                int P = piB + (k + 2) * 32;
                wC_ = scr_w[P]; pC_ = scr_o[P];
            }
            uint4 n00 = {}, n01 = {}, n10 = {}, n11 = {};
            if (k + 1 < 18) {
                const unsigned char* a0 = xb + (pB_ & 0x3FFFFF) + cq * 16;
                int dxb = (pB_ >> 15) & 128;
                int dyb = (pB_ >> 9)  & 16384;
                n00 = *(const uint4*)(a0);
                n01 = *(const uint4*)(a0 + dxb);
                n10 = *(const uint4*)(a0 + dyb);
                n11 = *(const uint4*)(a0 + dyb + dxb);
            }
            h2 w00 = bcast_lo(wA_.x), w01 = bcast_hi(wA_.x);
            h2 w10 = bcast_lo(wA_.y), w11 = bcast_hi(wA_.y);
            uint4 o4; h2 r;
            r = w00*u2h(a00.x) + w01*u2h(a01.x) + w10*u2h(a10.x) + w11*u2h(a11.x); o4.x = h2u(r);
            r = w00*u2h(a00.y) + w01*u2h(a01.y) + w10*u2h(a10.y) + w11*u2h(a11.y); o4.y = h2u(r);
            r = w00*u2h(a00.z) + w01*u2h(a01.z) + w10*u2h(a10.z) + w11*u2h(a11.z); o4.z = h2u(r);
            r = w00*u2h(a00.w) + w01*u2h(a01.w) + w10*u2h(a10.w) + w11*u2h(a11.w); o4.w = h2u(r);
            int sp  = (piB + (k & 1) * 32) & 63;
            int ktl = it6 >> 1;
            *(uint4*)&sS[sp * SSTR4 + ktl * 128 + cq * 16] = o4;
            wA_ = wB_; wB_ = wC_; pB_ = pC_;
            a00 = n00; a01 = n01; a10 = n10; a11 = n11;
        }
        f16x8 Af[6];
        #pragma unroll
        for (int s = 0; s < 6; ++s)
            Af[s] = *(const f16x8*)(w_bf + (o0 + m) * CK_ + (chunk * 6 + s) * 32 + q * 8);
        __syncthreads();

        #pragma unroll
        for (int s = 0; s < 6; ++s) {
            #pragma unroll
            for (int nt = 0; nt < 4; ++nt) {
                f16x8 bb = *(const f16x8*)&sS[(nt * 16 + m) * SSTR4 + s * 64 + q * 16];
                acc[nt] = __builtin_amdgcn_mfma_f32_16x16x32_f16(Af[s], bb, acc[nt], 0, 0, 0);
            }
        }
        __syncthreads();
    }

    #pragma unroll
    for (int nt = 0; nt < 4; ++nt) {
        #pragma unroll
        for (int r = 0; r < 4; ++r) {
            int o = o0 + q * 4 + r;
            out[((size_t)(b * CO_ + o)) * HW_ + p0 + nt * 16 + m] = acc[nt][r];
        }
    }
}

extern "C" void kernel_launch(void* const* d_in, const int* in_sizes, int n_in,
                              void* d_out, int out_size, void* d_ws, size_t ws_size,
                              hipStream_t stream)
{
    const float* x     = (const float*)d_in[0];
    const float* w_off = (const float*)d_in[1];
    const float* b_off = (const float*)d_in[2];
    const float* w_dcn = (const float*)d_in[3];
    float* out = (float*)d_out;

    unsigned short* xt   = (unsigned short*)d_ws;                // 16.8 MB
    unsigned short* w_bf = xt + (size_t)B_ * HW_ * 64;           // 73.7 KB
    unsigned short* wA   = w_bf + 64 * CK_;                      // 36.9 KB

    transpose_prep<<<B_ * 256 + 216, 256, 0, stream>>>(x, xt, w_dcn, w_off, w_bf, wA);
    dcn15<<<B_ * 256, 256, 0, stream>>>(xt, wA, b_off, w_bf, out);
}